// Round 2
// baseline (374.033 us; speedup 1.0000x reference)
//
#include <hip/hip_runtime.h>
#include <hip/hip_bf16.h>

// Factorized Tucker pipeline (fp32 inputs/output per reference; bf16 internally):
//   K1 : W1T[t][k][j] = sum_m task[t][m] * tensor[m][j][k]           (bf16, 64 KB)
//   K1b: W2T[t][k][i] = sum_j in_core[i][j] * W1[t][j][k]   (MFMA)   (bf16, 4 MB)
//   K2 : p2[t][b][k]  = sum_i x[b*8+t][i] * W2[t][i][k]     (MFMA)   (bf16, 1 MB)
//   K4 : y[b*8+t][o]  = sum_k p2[t][b][k] * out_core[o][k]  (MFMA)   (f32 out)
// fp32 operands are converted to bf16 in registers at point of use; MFMA
// accumulates in fp32. All frag loads are contiguous 16B-aligned vectors.

typedef __bf16 bf16;
typedef __bf16 bf16x8 __attribute__((ext_vector_type(8)));
typedef float  f32x4  __attribute__((ext_vector_type(4)));

__device__ __forceinline__ bf16x8 load_frag_bf16(const bf16* p) {
    return *reinterpret_cast<const bf16x8*>(p);
}

// 8 contiguous f32 -> bf16x8 frag (two dwordx4 loads + v_cvt).
__device__ __forceinline__ bf16x8 load_frag_f32(const float* p) {
    f32x4 a = *reinterpret_cast<const f32x4*>(p);
    f32x4 b = *reinterpret_cast<const f32x4*>(p + 4);
    bf16x8 r;
    r[0] = (bf16)a[0]; r[1] = (bf16)a[1]; r[2] = (bf16)a[2]; r[3] = (bf16)a[3];
    r[4] = (bf16)b[0]; r[5] = (bf16)b[1]; r[6] = (bf16)b[2]; r[7] = (bf16)b[3];
    return r;
}

__device__ __forceinline__ f32x4 mfma16(bf16x8 a, bf16x8 b, f32x4 c) {
    return __builtin_amdgcn_mfma_f32_16x16x32_bf16(a, b, c, 0, 0, 0);
}

// ---------------------------------------------------------------- K1
// grid 128 x 256. block = (t, part): 256 elements of W1T[t]. fp32 math.
__global__ __launch_bounds__(256) void k1_w1t(
    const float* __restrict__ task,   // [8][64]
    const float* __restrict__ tensor, // [64][64][64]  (m, j, k)
    bf16* __restrict__ w1t)           // [8][64][64]   (t, k, j)
{
    int t    = blockIdx.x >> 4;
    int part = blockIdx.x & 15;
    int idx  = part * 256 + threadIdx.x;  // 0..4095
    int j    = idx >> 6;
    int k    = idx & 63;                  // lanes consecutive in k -> coalesced
    float acc = 0.f;
    #pragma unroll 8
    for (int m = 0; m < 64; ++m)
        acc += task[t * 64 + m] * tensor[(m * 64 + j) * 64 + k];
    w1t[(t * 64 + k) * 64 + j] = (bf16)acc;
}

// ---------------------------------------------------------------- K1b
// grid 512 x 256. Per t: M=4096(i), N=64(k), K=64(j). Wave: 16 rows x 64 cols.
__global__ __launch_bounds__(256) void k1b_w2t(
    const float* __restrict__ in_core, // [4096][64]  (i, j) fp32
    const bf16* __restrict__ w1t,      // [8][64][64] (t, k, j)
    bf16* __restrict__ w2t)            // [8][64][4096] (t, k, i)
{
    int t    = blockIdx.x >> 6;
    int i0   = (blockIdx.x & 63) * 64 + (threadIdx.x >> 6) * 16;
    int lane = threadIdx.x & 63;
    int m    = lane & 15;
    int q    = lane >> 4;

    f32x4 acc[4] = {};
    #pragma unroll
    for (int kc = 0; kc < 64; kc += 32) {
        bf16x8 a = load_frag_f32(in_core + (i0 + m) * 64 + kc + q * 8);
        #pragma unroll
        for (int nt = 0; nt < 4; ++nt) {
            bf16x8 b = load_frag_bf16(w1t + (t * 64 + nt * 16 + m) * 64 + kc + q * 8);
            acc[nt] = mfma16(a, b, acc[nt]);
        }
    }
    #pragma unroll
    for (int nt = 0; nt < 4; ++nt) {
        int n = nt * 16 + m;           // C/D col = lane&15
        #pragma unroll
        for (int r = 0; r < 4; ++r) {
            int irow = i0 + q * 4 + r; // C/D row = quad*4 + reg
            w2t[(size_t)(t * 64 + n) * 4096 + irow] = (bf16)acc[nt][r];
        }
    }
}

// ---------------------------------------------------------------- K2
// grid 512 x 256. block = (t, 16 b-rows); wave w covers n0 = w*16.
// M-tile 16, N 64, K 4096. Barrier-free, no LDS. x converted inline.
__global__ __launch_bounds__(256) void k2_p2(
    const float* __restrict__ x,   // [1024][8][4096] fp32
    const bf16* __restrict__ w2t,  // [8][64][4096] (t, k, i)
    bf16* __restrict__ p2)         // [8][1024][64] (t, b, k)
{
    int t    = blockIdx.x >> 6;
    int b0   = (blockIdx.x & 63) * 16;
    int wave = threadIdx.x >> 6;
    int lane = threadIdx.x & 63;
    int m    = lane & 15;
    int q    = lane >> 4;
    int n0   = wave * 16;

    const float* arow = x   + (size_t)((b0 + m) * 8 + t) * 4096 + q * 8;
    const bf16*  brow = w2t + (size_t)(t * 64 + n0 + m) * 4096 + q * 8;

    f32x4 acc = {};
    #pragma unroll 4
    for (int kc = 0; kc < 4096; kc += 32) {
        bf16x8 a = load_frag_f32(arow + kc);
        bf16x8 b = load_frag_bf16(brow + kc);
        acc = mfma16(a, b, acc);
    }
    #pragma unroll
    for (int r = 0; r < 4; ++r) {
        int b = b0 + q * 4 + r;
        p2[(size_t)(t * 1024 + b) * 64 + n0 + m] = (bf16)acc[r];
    }
}

// ---------------------------------------------------------------- K4
// grid 2048 x 256. Per t: M=1024(b), N=4096(o), K=64. Block 128x128 tile;
// wave: 32 rows x 128 cols (2 m-subtiles x 8 n-subtiles), K=2 chunks.
__global__ __launch_bounds__(256) void k4_y(
    const float* __restrict__ p2_unused, // placeholder (keep signature simple)
    const bf16* __restrict__ p2,         // [8][1024][64]
    const float* __restrict__ out_core,  // [4096][64]  (o, k) fp32
    float* __restrict__ y)               // [1024][8][4096] fp32
{
    int bx    = blockIdx.x;
    int t     = bx >> 8;          // 256 blocks per t
    int rest  = bx & 255;
    int mtile = rest >> 5;        // 0..7
    int ntile = rest & 31;        // 0..31
    int wave  = threadIdx.x >> 6;
    int lane  = threadIdx.x & 63;
    int m     = lane & 15;
    int q     = lane >> 4;

    int b_base = mtile * 128 + wave * 32;
    int n_base = ntile * 128;

    f32x4 acc[2][8] = {};
    #pragma unroll
    for (int kc = 0; kc < 64; kc += 32) {
        bf16x8 a0 = load_frag_bf16(p2 + (size_t)(t * 1024 + b_base + m) * 64 + kc + q * 8);
        bf16x8 a1 = load_frag_bf16(p2 + (size_t)(t * 1024 + b_base + 16 + m) * 64 + kc + q * 8);
        #pragma unroll
        for (int nt = 0; nt < 8; ++nt) {
            bf16x8 b = load_frag_f32(out_core + (size_t)(n_base + nt * 16 + m) * 64 + kc + q * 8);
            acc[0][nt] = mfma16(a0, b, acc[0][nt]);
            acc[1][nt] = mfma16(a1, b, acc[1][nt]);
        }
    }
    #pragma unroll
    for (int sub = 0; sub < 2; ++sub) {
        #pragma unroll
        for (int nt = 0; nt < 8; ++nt) {
            int o = n_base + nt * 16 + m;
            #pragma unroll
            for (int r = 0; r < 4; ++r) {
                int b = b_base + sub * 16 + q * 4 + r;
                y[(size_t)(b * 8 + t) * 4096 + o] = acc[sub][nt][r];
            }
        }
    }
}

// ----------------------------------------------------------------
extern "C" void kernel_launch(void* const* d_in, const int* in_sizes, int n_in,
                              void* d_out, int out_size, void* d_ws, size_t ws_size,
                              hipStream_t stream) {
    // setup_inputs order: x, tensor_core, task_core, in_core, out_core (all fp32)
    const float* x        = (const float*)d_in[0];
    const float* tensor_c = (const float*)d_in[1];
    const float* task_c   = (const float*)d_in[2];
    const float* in_c     = (const float*)d_in[3];
    const float* out_c    = (const float*)d_in[4];
    float* y = (float*)d_out;

    char* ws = (char*)d_ws;
    bf16* w1t = (bf16*)ws;                                   // 8*64*64*2   = 64 KB
    bf16* w2t = (bf16*)(ws + 65536);                         // 8*64*4096*2 = 4 MB
    bf16* p2  = (bf16*)(ws + 65536 + (size_t)8*64*4096*2);   // 8*1024*64*2 = 1 MB

    k1_w1t <<<128,  256, 0, stream>>>(task_c, tensor_c, w1t);
    k1b_w2t<<<512,  256, 0, stream>>>(in_c, w1t, w2t);
    k2_p2  <<<512,  256, 0, stream>>>(x, w2t, p2);
    k4_y   <<<2048, 256, 0, stream>>>(nullptr, p2, out_c, y);
}

// Round 3
// 331.342 us; speedup vs baseline: 1.1288x; 1.1288x over previous
//
#include <hip/hip_runtime.h>
#include <hip/hip_bf16.h>

// Factorized Tucker pipeline (fp32 inputs/output per reference; bf16 internally):
//   K1 : W1T[t][k][j] = sum_m task[t][m] * tensor[m][j][k]           (bf16, 64 KB)
//   K1b: W2T[t][k][i] = sum_j in_core[i][j] * W1[t][j][k]   (MFMA)   (bf16, 4 MB)
//   K2 : pp[s][t][b][k] = partial sum_i x[b*8+t][i]*W2[t][i][k] (MFMA, f32, K-split)
//   KR : p2[t][b][k]  = bf16( sum_s pp[s][t][b][k] )
//   K4 : y[b*8+t][o]  = sum_k p2[t][b][k] * out_core[o][k]  (MFMA)   (f32 out)
// K2 v2: K-split (occupancy 8 -> ~24-32 waves/CU) + manual 4x load batching
// (12 outstanding 16B loads/wave) to fix the round-2 latency bind (VGPR=12,
// 588 GB/s). All frag loads are contiguous 16B-aligned vectors.

typedef __bf16 bf16;
typedef __bf16 bf16x8 __attribute__((ext_vector_type(8)));
typedef __bf16 bf16x4 __attribute__((ext_vector_type(4)));
typedef float  f32x4  __attribute__((ext_vector_type(4)));

__device__ __forceinline__ bf16x8 load_frag_bf16(const bf16* p) {
    return *reinterpret_cast<const bf16x8*>(p);
}

// 8 contiguous f32 -> bf16x8 frag (two dwordx4 loads + v_cvt).
__device__ __forceinline__ bf16x8 load_frag_f32(const float* p) {
    f32x4 a = *reinterpret_cast<const f32x4*>(p);
    f32x4 b = *reinterpret_cast<const f32x4*>(p + 4);
    bf16x8 r;
    r[0] = (bf16)a[0]; r[1] = (bf16)a[1]; r[2] = (bf16)a[2]; r[3] = (bf16)a[3];
    r[4] = (bf16)b[0]; r[5] = (bf16)b[1]; r[6] = (bf16)b[2]; r[7] = (bf16)b[3];
    return r;
}

__device__ __forceinline__ f32x4 mfma16(bf16x8 a, bf16x8 b, f32x4 c) {
    return __builtin_amdgcn_mfma_f32_16x16x32_bf16(a, b, c, 0, 0, 0);
}

// ---------------------------------------------------------------- K1
// grid 128 x 256. block = (t, part): 256 elements of W1T[t]. fp32 math.
__global__ __launch_bounds__(256) void k1_w1t(
    const float* __restrict__ task,   // [8][64]
    const float* __restrict__ tensor, // [64][64][64]  (m, j, k)
    bf16* __restrict__ w1t)           // [8][64][64]   (t, k, j)
{
    int t    = blockIdx.x >> 4;
    int part = blockIdx.x & 15;
    int idx  = part * 256 + threadIdx.x;  // 0..4095
    int j    = idx >> 6;
    int k    = idx & 63;                  // lanes consecutive in k -> coalesced
    float acc = 0.f;
    #pragma unroll 8
    for (int m = 0; m < 64; ++m)
        acc += task[t * 64 + m] * tensor[(m * 64 + j) * 64 + k];
    w1t[(t * 64 + k) * 64 + j] = (bf16)acc;
}

// ---------------------------------------------------------------- K1b
// grid 512 x 256. Per t: M=4096(i), N=64(k), K=64(j). Wave: 16 rows x 64 cols.
__global__ __launch_bounds__(256) void k1b_w2t(
    const float* __restrict__ in_core, // [4096][64]  (i, j) fp32
    const bf16* __restrict__ w1t,      // [8][64][64] (t, k, j)
    bf16* __restrict__ w2t)            // [8][64][4096] (t, k, i)
{
    int t    = blockIdx.x >> 6;
    int i0   = (blockIdx.x & 63) * 64 + (threadIdx.x >> 6) * 16;
    int lane = threadIdx.x & 63;
    int m    = lane & 15;
    int q    = lane >> 4;

    f32x4 acc[4] = {};
    #pragma unroll
    for (int kc = 0; kc < 64; kc += 32) {
        bf16x8 a = load_frag_f32(in_core + (i0 + m) * 64 + kc + q * 8);
        #pragma unroll
        for (int nt = 0; nt < 4; ++nt) {
            bf16x8 b = load_frag_bf16(w1t + (t * 64 + nt * 16 + m) * 64 + kc + q * 8);
            acc[nt] = mfma16(a, b, acc[nt]);
        }
    }
    #pragma unroll
    for (int nt = 0; nt < 4; ++nt) {
        int n = nt * 16 + m;           // C/D col = lane&15
        #pragma unroll
        for (int r = 0; r < 4; ++r) {
            int irow = i0 + q * 4 + r; // C/D row = quad*4 + reg
            w2t[(size_t)(t * 64 + n) * 4096 + irow] = (bf16)acc[nt][r];
        }
    }
}

// ---------------------------------------------------------------- K2
// grid (512*KS) x 256. block = (ks, t, 16 b-rows); wave w covers n0 = w*16.
// K-split: each block sums a kchunk of the K=4096 contraction into f32
// partials. Manual 4x batch: 12 independent 16B loads in flight per step.
__global__ __launch_bounds__(256) void k2_p2(
    const float* __restrict__ x,   // [1024][8][4096] fp32
    const bf16* __restrict__ w2t,  // [8][64][4096] (t, k, i)
    float* __restrict__ pp,        // [KS][8][1024][64] f32 partials
    int kchunk)                    // 4096 / KS, multiple of 128
{
    int ks   = blockIdx.x >> 9;          // blockIdx / 512
    int rem  = blockIdx.x & 511;
    int t    = rem >> 6;
    int b0   = (rem & 63) * 16;
    int wave = threadIdx.x >> 6;
    int lane = threadIdx.x & 63;
    int m    = lane & 15;
    int q    = lane >> 4;
    int n0   = wave * 16;

    int kbeg = ks * kchunk;
    const float* arow = x   + (size_t)((b0 + m) * 8 + t) * 4096 + kbeg + q * 8;
    const bf16*  brow = w2t + (size_t)(t * 64 + n0 + m) * 4096 + kbeg + q * 8;

    f32x4 acc = {};
    for (int kc = 0; kc < kchunk; kc += 128) {
        bf16x8 a[4], b[4];
        #pragma unroll
        for (int u = 0; u < 4; ++u) {
            a[u] = load_frag_f32(arow + kc + u * 32);
            b[u] = load_frag_bf16(brow + kc + u * 32);
        }
        #pragma unroll
        for (int u = 0; u < 4; ++u)
            acc = mfma16(a[u], b[u], acc);
    }
    float* dst = pp + (size_t)ks * 524288 + (size_t)(t * 1024 + b0) * 64;
    #pragma unroll
    for (int r = 0; r < 4; ++r)
        dst[(q * 4 + r) * 64 + n0 + m] = acc[r];
}

// ---------------------------------------------------------------- KR
// grid 512 x 256. p2 = bf16(sum over splits of pp). 4 elems/thread.
__global__ __launch_bounds__(256) void k_reduce(
    const float* __restrict__ pp,  // [nsplit][524288]
    bf16* __restrict__ p2,         // [524288]
    int nsplit)
{
    int idx = (blockIdx.x * 256 + threadIdx.x) * 4;
    f32x4 s = *reinterpret_cast<const f32x4*>(pp + idx);
    for (int sp = 1; sp < nsplit; ++sp)
        s += *reinterpret_cast<const f32x4*>(pp + (size_t)sp * 524288 + idx);
    bf16x4 o;
    o[0] = (bf16)s[0]; o[1] = (bf16)s[1]; o[2] = (bf16)s[2]; o[3] = (bf16)s[3];
    *reinterpret_cast<bf16x4*>(p2 + idx) = o;
}

// ---------------------------------------------------------------- K4
// grid 2048 x 256. Per t: M=1024(b), N=4096(o), K=64. Block 128x128 tile;
// wave: 32 rows x 128 cols (2 m-subtiles x 8 n-subtiles), K=2 chunks.
__global__ __launch_bounds__(256) void k4_y(
    const bf16* __restrict__ p2,        // [8][1024][64]
    const float* __restrict__ out_core, // [4096][64]  (o, k) fp32
    float* __restrict__ y)              // [1024][8][4096] fp32
{
    int bx    = blockIdx.x;
    int t     = bx >> 8;          // 256 blocks per t
    int rest  = bx & 255;
    int mtile = rest >> 5;        // 0..7
    int ntile = rest & 31;        // 0..31
    int wave  = threadIdx.x >> 6;
    int lane  = threadIdx.x & 63;
    int m     = lane & 15;
    int q     = lane >> 4;

    int b_base = mtile * 128 + wave * 32;
    int n_base = ntile * 128;

    f32x4 acc[2][8] = {};
    #pragma unroll
    for (int kc = 0; kc < 64; kc += 32) {
        bf16x8 a0 = load_frag_bf16(p2 + (size_t)(t * 1024 + b_base + m) * 64 + kc + q * 8);
        bf16x8 a1 = load_frag_bf16(p2 + (size_t)(t * 1024 + b_base + 16 + m) * 64 + kc + q * 8);
        #pragma unroll
        for (int nt = 0; nt < 8; ++nt) {
            bf16x8 b = load_frag_f32(out_core + (size_t)(n_base + nt * 16 + m) * 64 + kc + q * 8);
            acc[0][nt] = mfma16(a0, b, acc[0][nt]);
            acc[1][nt] = mfma16(a1, b, acc[1][nt]);
        }
    }
    #pragma unroll
    for (int sub = 0; sub < 2; ++sub) {
        #pragma unroll
        for (int nt = 0; nt < 8; ++nt) {
            int o = n_base + nt * 16 + m;
            #pragma unroll
            for (int r = 0; r < 4; ++r) {
                int b = b_base + sub * 16 + q * 4 + r;
                y[(size_t)(b * 8 + t) * 4096 + o] = acc[sub][nt][r];
            }
        }
    }
}

// ----------------------------------------------------------------
extern "C" void kernel_launch(void* const* d_in, const int* in_sizes, int n_in,
                              void* d_out, int out_size, void* d_ws, size_t ws_size,
                              hipStream_t stream) {
    // setup_inputs order: x, tensor_core, task_core, in_core, out_core (all fp32)
    const float* x        = (const float*)d_in[0];
    const float* tensor_c = (const float*)d_in[1];
    const float* task_c   = (const float*)d_in[2];
    const float* in_c     = (const float*)d_in[3];
    const float* out_c    = (const float*)d_in[4];
    float* y = (float*)d_out;

    // Workspace layout (bytes):
    //   w1t: 65536 | w2t: 4 MiB | pp: KS*2 MiB f32 | p2: 1 MiB bf16
    char* ws = (char*)d_ws;
    bf16*  w1t = (bf16*)ws;
    bf16*  w2t = (bf16*)(ws + 65536);
    float* pp  = (float*)(ws + 65536 + (size_t)4 * 1024 * 1024);

    // Pick largest K-split that fits ws (deterministic across calls).
    int KS = 4;
    while (KS > 1) {
        size_t need = 65536 + (size_t)4*1024*1024 + (size_t)KS*2097152 + 1048576;
        if (need <= ws_size) break;
        KS >>= 1;
    }
    bf16* p2 = (bf16*)(ws + 65536 + (size_t)4*1024*1024 + (size_t)KS*2097152);
    int kchunk = 4096 / KS;

    k1_w1t  <<<128,      256, 0, stream>>>(task_c, tensor_c, w1t);
    k1b_w2t <<<512,      256, 0, stream>>>(in_c, w1t, w2t);
    k2_p2   <<<512 * KS, 256, 0, stream>>>(x, w2t, pp, kchunk);
    k_reduce<<<512,      256, 0, stream>>>(pp, p2, KS);
    k4_y    <<<2048,     256, 0, stream>>>(p2, out_c, y);
}